// Round 2
// baseline (494.203 us; speedup 1.0000x reference)
//
#include <hip/hip_runtime.h>
#include <math.h>

#define QMAXF 127.0f

struct Ptrs4 { const float* p[4]; };

__device__ __forceinline__ float qscale(float m) {
    return (m > 0.0f) ? (m / QMAXF) : 1.0f;
}

__device__ __forceinline__ float quant1(float x, float s) {
    float r = rintf(x / s);
    r = fminf(fmaxf(r, -QMAXF), QMAXF);
    return r * s;
}

// Block-wide max over all threads' v. All threads must call. sred >= 17 floats.
__device__ __forceinline__ float block_max_red(float v, float* sred) {
    #pragma unroll
    for (int off = 32; off > 0; off >>= 1)
        v = fmaxf(v, __shfl_down(v, off, 64));
    int wave = threadIdx.x >> 6;
    int lane = threadIdx.x & 63;
    __syncthreads();
    if (lane == 0) sred[wave] = v;
    __syncthreads();
    if (threadIdx.x == 0) {
        int nw = blockDim.x >> 6;
        float m = sred[0];
        for (int i = 1; i < nw; ++i) m = fmaxf(m, sred[i]);
        sred[16] = m;
    }
    __syncthreads();
    return sred[16];
}

__device__ __forceinline__ void quant_vec4(float* a, float* sred) {
    float pm = 0.0f;
    #pragma unroll
    for (int i = 0; i < 4; ++i) pm = fmaxf(pm, fabsf(a[i]));
    float s = qscale(block_max_red(pm, sred));
    #pragma unroll
    for (int i = 0; i < 4; ++i) a[i] = quant1(a[i], s);
}

// ---------------------------------------------------------------------------
// Kernel 1: quantize concat = Q([h, x]) (block 0) and the 4 biases (blocks 1-4).
// Also zeroes the 4 atomic-max slots (ws is poisoned 0xAA before each launch).
// ---------------------------------------------------------------------------
__global__ __launch_bounds__(1024) void k_prep(
    const float* __restrict__ x, const float* __restrict__ h,
    Ptrs4 biases, float* __restrict__ concat_q, float* __restrict__ qb,
    unsigned* __restrict__ gmax)
{
    __shared__ float sred[17];
    int tid = threadIdx.x;
    if (blockIdx.x == 0) {
        if (tid < 4) gmax[tid] = 0u;
        float vals[8];
        float pm = 0.0f;
        #pragma unroll
        for (int i = 0; i < 8; ++i) {
            int idx = i * 1024 + tid;
            float v = (i < 4) ? h[idx] : x[idx - 4096];  // concat = [h, inputs]
            vals[i] = v;
            pm = fmaxf(pm, fabsf(v));
        }
        float s = qscale(block_max_red(pm, sred));
        #pragma unroll
        for (int i = 0; i < 8; ++i) concat_q[i * 1024 + tid] = quant1(vals[i], s);
    } else {
        int g = blockIdx.x - 1;
        const float* __restrict__ b = biases.p[g];
        float vals[4];
        float pm = 0.0f;
        #pragma unroll
        for (int i = 0; i < 4; ++i) {
            float v = b[i * 1024 + tid];
            vals[i] = v;
            pm = fmaxf(pm, fabsf(v));
        }
        float s = qscale(block_max_red(pm, sred));
        #pragma unroll
        for (int i = 0; i < 4; ++i) qb[g * 4096 + i * 1024 + tid] = quant1(vals[i], s);
    }
}

// ---------------------------------------------------------------------------
// Kernel 2: GEMV partials. y[j] = sum_k xq[k] * W[k][j], W row-major [8192][4096].
// grid = (4 col-tiles, 64 k-chunks, 4 gates) = 1024 blocks -> 4 blocks/CU,
// 16 waves/CU. Each thread: 4 consecutive columns (float4), 64 k-rows, with an
// explicit 4-deep prefetch pipeline (4-8 global_load_dwordx4 in flight/wave).
// ---------------------------------------------------------------------------
#define KCHUNKS 64
#define KB      (8192 / KCHUNKS)   // 128 rows per chunk? no: 8192/64 = 128
// NOTE: KB computed = 128. Each thread iterates KB rows in groups of 4.

__global__ __launch_bounds__(256) void k_gemv(
    Ptrs4 wts, const float* __restrict__ xq, float* __restrict__ partials)
{
    int ct = blockIdx.x;   // 0..3    col tile (1024 cols)
    int kc = blockIdx.y;   // 0..63   k chunk (KB rows)
    int g  = blockIdx.z;   // 0..3    gate
    const float* __restrict__ W = wts.p[g];
    int col0 = ct * 1024 + threadIdx.x * 4;
    int k0 = kc * KB;
    const float* __restrict__ wrow = W + (size_t)k0 * 4096 + col0;
    const float* __restrict__ xp = xq + k0;

    float ax = 0.f, ay = 0.f, az = 0.f, aw = 0.f;
    float4 cur[4], nxt[4];

    #pragma unroll
    for (int j = 0; j < 4; ++j)
        cur[j] = *(const float4*)(wrow + (size_t)j * 4096);

    for (int kk = 0; kk < KB - 4; kk += 4) {
        // issue next group's 4 loads before consuming current group
        #pragma unroll
        for (int j = 0; j < 4; ++j)
            nxt[j] = *(const float4*)(wrow + (size_t)(kk + 4 + j) * 4096);
        #pragma unroll
        for (int j = 0; j < 4; ++j) {
            float xv = xp[kk + j];          // wave-uniform -> scalar load
            ax = fmaf(xv, cur[j].x, ax);
            ay = fmaf(xv, cur[j].y, ay);
            az = fmaf(xv, cur[j].z, az);
            aw = fmaf(xv, cur[j].w, aw);
        }
        #pragma unroll
        for (int j = 0; j < 4; ++j) cur[j] = nxt[j];
    }
    // tail group (kk = KB-4)
    #pragma unroll
    for (int j = 0; j < 4; ++j) {
        float xv = xp[KB - 4 + j];
        ax = fmaf(xv, cur[j].x, ax);
        ay = fmaf(xv, cur[j].y, ay);
        az = fmaf(xv, cur[j].z, az);
        aw = fmaf(xv, cur[j].w, aw);
    }

    float4 r; r.x = ax; r.y = ay; r.z = az; r.w = aw;
    *(float4*)(partials + (size_t)(g * KCHUNKS + kc) * 4096 + col0) = r;
}

// ---------------------------------------------------------------------------
// Kernel 3: reduce KCHUNKS partials per column; per-gate max|y| via atomicMax.
// grid = 64 blocks (gate = b>>4, colblock = b&15), block = 256.
// ---------------------------------------------------------------------------
__global__ __launch_bounds__(256) void k_reduce(
    const float* __restrict__ partials, float* __restrict__ y,
    unsigned* __restrict__ gmax)
{
    int g  = blockIdx.x >> 4;
    int cb = blockIdx.x & 15;
    int col = cb * 256 + threadIdx.x;
    float s = 0.0f;
    #pragma unroll 8
    for (int kc = 0; kc < KCHUNKS; ++kc)
        s += partials[(size_t)(g * KCHUNKS + kc) * 4096 + col];
    y[g * 4096 + col] = s;

    float m = fabsf(s);
    #pragma unroll
    for (int off = 32; off > 0; off >>= 1)
        m = fmaxf(m, __shfl_down(m, off, 64));
    __shared__ float sm[4];
    int wave = threadIdx.x >> 6, lane = threadIdx.x & 63;
    if (lane == 0) sm[wave] = m;
    __syncthreads();
    if (threadIdx.x == 0) {
        float mm = fmaxf(fmaxf(sm[0], sm[1]), fmaxf(sm[2], sm[3]));
        atomicMax(gmax + g, __float_as_uint(mm));
    }
}

// ---------------------------------------------------------------------------
// Kernel 4: full quantized LSTM epilogue on one block (1024 thr x 4 elems/gate).
// gates: 0=f, 1=i, 2=c(candidate, tanh), 3=o
// ---------------------------------------------------------------------------
__global__ __launch_bounds__(1024) void k_epilogue(
    const float* __restrict__ y, const float* __restrict__ qb,
    const unsigned* __restrict__ gmax, const float* __restrict__ c,
    float* __restrict__ out)
{
    __shared__ float sred[17];
    int tid = threadIdx.x;
    float v[4][4];

    // q1 = Q(x@W); yb = q1 + Q(b)
    #pragma unroll
    for (int g = 0; g < 4; ++g) {
        float s = qscale(__uint_as_float(gmax[g]));
        #pragma unroll
        for (int i = 0; i < 4; ++i) {
            int col = i * 1024 + tid;
            v[g][i] = quant1(y[g * 4096 + col], s) + qb[g * 4096 + col];
        }
    }

    // q2 = Q(yb); act = tanh/sigmoid(q2)
    for (int g = 0; g < 4; ++g) {
        float pm = 0.0f;
        #pragma unroll
        for (int i = 0; i < 4; ++i) pm = fmaxf(pm, fabsf(v[g][i]));
        float s = qscale(block_max_red(pm, sred));
        #pragma unroll
        for (int i = 0; i < 4; ++i) {
            float q = quant1(v[g][i], s);
            v[g][i] = (g == 2) ? tanhf(q) : (1.0f / (1.0f + expf(-q)));
        }
    }

    // q3 = Q(act)  -> v[0]=zf, v[1]=zi, v[2]=z, v[3]=zo
    for (int g = 0; g < 4; ++g) {
        float pm = 0.0f;
        #pragma unroll
        for (int i = 0; i < 4; ++i) pm = fmaxf(pm, fabsf(v[g][i]));
        float s = qscale(block_max_red(pm, sred));
        #pragma unroll
        for (int i = 0; i < 4; ++i) v[g][i] = quant1(v[g][i], s);
    }

    // memory = Q(z * zi)
    float mem[4];
    #pragma unroll
    for (int i = 0; i < 4; ++i) mem[i] = v[2][i] * v[1][i];
    quant_vec4(mem, sred);

    // cf = Q(c * zf)
    float cf[4];
    #pragma unroll
    for (int i = 0; i < 4; ++i) cf[i] = c[i * 1024 + tid] * v[0][i];
    quant_vec4(cf, sred);

    // c_new = Q(cf + memory)
    float cn[4];
    #pragma unroll
    for (int i = 0; i < 4; ++i) cn[i] = cf[i] + mem[i];
    quant_vec4(cn, sred);

    // t = Q(tanh(c_new))
    float tc[4];
    #pragma unroll
    for (int i = 0; i < 4; ++i) tc[i] = tanhf(cn[i]);
    quant_vec4(tc, sred);

    // h_new = Q(zo * t)
    float hn[4];
    #pragma unroll
    for (int i = 0; i < 4; ++i) hn[i] = v[3][i] * tc[i];
    quant_vec4(hn, sred);
    #pragma unroll
    for (int i = 0; i < 4; ++i) out[i * 1024 + tid] = hn[i];
}

// ---------------------------------------------------------------------------
extern "C" void kernel_launch(void* const* d_in, const int* in_sizes, int n_in,
                              void* d_out, int out_size, void* d_ws, size_t ws_size,
                              hipStream_t stream) {
    const float* x = (const float*)d_in[0];   // inputs [1,4096]
    const float* c = (const float*)d_in[1];   // c      [1,4096]
    const float* h = (const float*)d_in[2];   // h      [1,4096]
    Ptrs4 wts, bs;
    wts.p[0] = (const float*)d_in[3];  bs.p[0] = (const float*)d_in[4];   // Wf
    wts.p[1] = (const float*)d_in[5];  bs.p[1] = (const float*)d_in[6];   // Wi
    wts.p[2] = (const float*)d_in[7];  bs.p[2] = (const float*)d_in[8];   // Wc
    wts.p[3] = (const float*)d_in[9];  bs.p[3] = (const float*)d_in[10];  // Wo

    float* ws = (float*)d_ws;
    float* partials = ws;                           // 4*64*4096 = 1048576 floats (4 MiB)
    float* concat_q = ws + 1048576;                 // 8192 floats
    float* qb       = ws + 1048576 + 8192;          // 16384 floats
    float* yv       = ws + 1048576 + 8192 + 16384;  // 16384 floats
    unsigned* gmax  = (unsigned*)(ws + 1048576 + 8192 + 16384 + 16384);

    hipLaunchKernelGGL(k_prep,     dim3(5),              dim3(1024), 0, stream,
                       x, h, bs, concat_q, qb, gmax);
    hipLaunchKernelGGL(k_gemv,     dim3(4, KCHUNKS, 4),  dim3(256),  0, stream,
                       wts, concat_q, partials);
    hipLaunchKernelGGL(k_reduce,   dim3(64),             dim3(256),  0, stream,
                       partials, yv, gmax);
    hipLaunchKernelGGL(k_epilogue, dim3(1),              dim3(1024), 0, stream,
                       yv, qb, gmax, c, (float*)d_out);
}

// Round 3
// 472.367 us; speedup vs baseline: 1.0462x; 1.0462x over previous
//
#include <hip/hip_runtime.h>
#include <math.h>

#define QMAXF 127.0f

struct Ptrs4 { const float* p[4]; };

__device__ __forceinline__ float qscale(float m) {
    return (m > 0.0f) ? (m / QMAXF) : 1.0f;
}

__device__ __forceinline__ float quant1(float x, float s) {
    float r = rintf(x / s);
    r = fminf(fmaxf(r, -QMAXF), QMAXF);
    return r * s;
}

// Block-wide max over all threads' v. All threads must call. sred >= 17 floats.
__device__ __forceinline__ float block_max_red(float v, float* sred) {
    #pragma unroll
    for (int off = 32; off > 0; off >>= 1)
        v = fmaxf(v, __shfl_down(v, off, 64));
    int wave = threadIdx.x >> 6;
    int lane = threadIdx.x & 63;
    __syncthreads();
    if (lane == 0) sred[wave] = v;
    __syncthreads();
    if (threadIdx.x == 0) {
        int nw = blockDim.x >> 6;
        float m = sred[0];
        for (int i = 1; i < nw; ++i) m = fmaxf(m, sred[i]);
        sred[16] = m;
    }
    __syncthreads();
    return sred[16];
}

__device__ __forceinline__ void quant_vec4(float* a, float* sred) {
    float pm = 0.0f;
    #pragma unroll
    for (int i = 0; i < 4; ++i) pm = fmaxf(pm, fabsf(a[i]));
    float s = qscale(block_max_red(pm, sred));
    #pragma unroll
    for (int i = 0; i < 4; ++i) a[i] = quant1(a[i], s);
}

// ---------------------------------------------------------------------------
// Kernel 1: quantize concat = Q([h, x]) (block 0) and the 4 biases (blocks 1-4).
// Also zeroes the 4 atomic-max slots (ws is poisoned 0xAA before each launch).
// ---------------------------------------------------------------------------
__global__ __launch_bounds__(1024) void k_prep(
    const float* __restrict__ x, const float* __restrict__ h,
    Ptrs4 biases, float* __restrict__ concat_q, float* __restrict__ qb,
    unsigned* __restrict__ gmax)
{
    __shared__ float sred[17];
    int tid = threadIdx.x;
    if (blockIdx.x == 0) {
        if (tid < 4) gmax[tid] = 0u;
        float vals[8];
        float pm = 0.0f;
        #pragma unroll
        for (int i = 0; i < 8; ++i) {
            int idx = i * 1024 + tid;
            float v = (i < 4) ? h[idx] : x[idx - 4096];  // concat = [h, inputs]
            vals[i] = v;
            pm = fmaxf(pm, fabsf(v));
        }
        float s = qscale(block_max_red(pm, sred));
        #pragma unroll
        for (int i = 0; i < 8; ++i) concat_q[i * 1024 + tid] = quant1(vals[i], s);
    } else {
        int g = blockIdx.x - 1;
        const float* __restrict__ b = biases.p[g];
        float vals[4];
        float pm = 0.0f;
        #pragma unroll
        for (int i = 0; i < 4; ++i) {
            float v = b[i * 1024 + tid];
            vals[i] = v;
            pm = fmaxf(pm, fabsf(v));
        }
        float s = qscale(block_max_red(pm, sred));
        #pragma unroll
        for (int i = 0; i < 4; ++i) qb[g * 4096 + i * 1024 + tid] = quant1(vals[i], s);
    }
}

// ---------------------------------------------------------------------------
// Kernel 2: GEMV partials, wave-contiguous streaming.
// W row-major [8192][4096] (16 KiB rows). Each WAVE reads full rows
// contiguously: lane l, instr i -> float4 at floats [i*256 + l*4] of the row.
// Each thread keeps 16 float4 accums (cols i*256 + l*4 .. +3).
// Block = 256 thr (4 waves); block owns 128 consecutive rows; wave w handles
// rows w, w+4, ... (32 rows), 2-row explicit double buffer (~16-32 KiB
// in flight per wave). Cross-wave sum via LDS, coalesced float4 store.
// grid = (64 kchunks, 4 gates) = 256 blocks.
// ---------------------------------------------------------------------------
#define KCHUNKS 64
#define RPB (8192 / KCHUNKS)   // 128 rows per block
#define RPW (RPB / 4)          // 32 rows per wave

__global__ __launch_bounds__(256, 1) void k_gemv(
    Ptrs4 wts, const float* __restrict__ xq, float* __restrict__ partials)
{
    int kc = blockIdx.x;   // 0..63  k chunk
    int g  = blockIdx.y;   // 0..3   gate
    const float* __restrict__ W = wts.p[g];
    int wave = threadIdx.x >> 6;
    int lane = threadIdx.x & 63;

    const float* __restrict__ rbase =
        W + (size_t)(kc * RPB + wave) * 4096 + lane * 4;     // row (wave), step 4 rows
    const float* __restrict__ xp = xq + kc * RPB + wave;     // wave-uniform scalar

    float4 acc[16];
    #pragma unroll
    for (int i = 0; i < 16; ++i) acc[i] = make_float4(0.f, 0.f, 0.f, 0.f);

    float4 bufA[16], bufB[16];
    #pragma unroll
    for (int i = 0; i < 16; ++i)
        bufA[i] = *(const float4*)(rbase + i * 256);         // row 0 (of this wave)

    for (int r = 0; r < RPW - 2; r += 2) {
        const float* b1 = rbase + (size_t)(r + 1) * 4 * 4096;
        #pragma unroll
        for (int i = 0; i < 16; ++i)
            bufB[i] = *(const float4*)(b1 + i * 256);        // prefetch row r+1
        float xv0 = xp[4 * r];
        #pragma unroll
        for (int i = 0; i < 16; ++i) {
            acc[i].x = fmaf(xv0, bufA[i].x, acc[i].x);
            acc[i].y = fmaf(xv0, bufA[i].y, acc[i].y);
            acc[i].z = fmaf(xv0, bufA[i].z, acc[i].z);
            acc[i].w = fmaf(xv0, bufA[i].w, acc[i].w);
        }
        const float* b2 = rbase + (size_t)(r + 2) * 4 * 4096;
        #pragma unroll
        for (int i = 0; i < 16; ++i)
            bufA[i] = *(const float4*)(b2 + i * 256);        // prefetch row r+2
        float xv1 = xp[4 * (r + 1)];
        #pragma unroll
        for (int i = 0; i < 16; ++i) {
            acc[i].x = fmaf(xv1, bufB[i].x, acc[i].x);
            acc[i].y = fmaf(xv1, bufB[i].y, acc[i].y);
            acc[i].z = fmaf(xv1, bufB[i].z, acc[i].z);
            acc[i].w = fmaf(xv1, bufB[i].w, acc[i].w);
        }
    }
    // tail: rows RPW-2 (in bufA) and RPW-1
    {
        const float* b1 = rbase + (size_t)(RPW - 1) * 4 * 4096;
        #pragma unroll
        for (int i = 0; i < 16; ++i)
            bufB[i] = *(const float4*)(b1 + i * 256);
        float xv0 = xp[4 * (RPW - 2)];
        #pragma unroll
        for (int i = 0; i < 16; ++i) {
            acc[i].x = fmaf(xv0, bufA[i].x, acc[i].x);
            acc[i].y = fmaf(xv0, bufA[i].y, acc[i].y);
            acc[i].z = fmaf(xv0, bufA[i].z, acc[i].z);
            acc[i].w = fmaf(xv0, bufA[i].w, acc[i].w);
        }
        float xv1 = xp[4 * (RPW - 1)];
        #pragma unroll
        for (int i = 0; i < 16; ++i) {
            acc[i].x = fmaf(xv1, bufB[i].x, acc[i].x);
            acc[i].y = fmaf(xv1, bufB[i].y, acc[i].y);
            acc[i].z = fmaf(xv1, bufB[i].z, acc[i].z);
            acc[i].w = fmaf(xv1, bufB[i].w, acc[i].w);
        }
    }

    // Cross-wave reduction via LDS: red[wave][col], col = i*256 + lane*4.
    __shared__ float red[4][4096];   // 64 KiB
    #pragma unroll
    for (int i = 0; i < 16; ++i)
        *(float4*)&red[wave][i * 256 + lane * 4] = acc[i];
    __syncthreads();

    // Each thread sums 4 waves for 4 float4s, coalesced global store.
    float* __restrict__ pout = partials + (size_t)(g * KCHUNKS + kc) * 4096;
    int t = threadIdx.x;
    #pragma unroll
    for (int q = 0; q < 4; ++q) {
        int col = q * 1024 + t * 4;
        float4 s0 = *(const float4*)&red[0][col];
        float4 s1 = *(const float4*)&red[1][col];
        float4 s2 = *(const float4*)&red[2][col];
        float4 s3 = *(const float4*)&red[3][col];
        float4 r4;
        r4.x = (s0.x + s1.x) + (s2.x + s3.x);
        r4.y = (s0.y + s1.y) + (s2.y + s3.y);
        r4.z = (s0.z + s1.z) + (s2.z + s3.z);
        r4.w = (s0.w + s1.w) + (s2.w + s3.w);
        *(float4*)(pout + col) = r4;
    }
}

// ---------------------------------------------------------------------------
// Kernel 3: reduce KCHUNKS partials per column; per-gate max|y| via atomicMax.
// grid = 64 blocks (gate = b>>4, colblock = b&15), block = 256.
// ---------------------------------------------------------------------------
__global__ __launch_bounds__(256) void k_reduce(
    const float* __restrict__ partials, float* __restrict__ y,
    unsigned* __restrict__ gmax)
{
    int g  = blockIdx.x >> 4;
    int cb = blockIdx.x & 15;
    int col = cb * 256 + threadIdx.x;
    float s = 0.0f;
    #pragma unroll 8
    for (int kc = 0; kc < KCHUNKS; ++kc)
        s += partials[(size_t)(g * KCHUNKS + kc) * 4096 + col];
    y[g * 4096 + col] = s;

    float m = fabsf(s);
    #pragma unroll
    for (int off = 32; off > 0; off >>= 1)
        m = fmaxf(m, __shfl_down(m, off, 64));
    __shared__ float sm[4];
    int wave = threadIdx.x >> 6, lane = threadIdx.x & 63;
    if (lane == 0) sm[wave] = m;
    __syncthreads();
    if (threadIdx.x == 0) {
        float mm = fmaxf(fmaxf(sm[0], sm[1]), fmaxf(sm[2], sm[3]));
        atomicMax(gmax + g, __float_as_uint(mm));
    }
}

// ---------------------------------------------------------------------------
// Kernel 4: full quantized LSTM epilogue on one block (1024 thr x 4 elems/gate).
// gates: 0=f, 1=i, 2=c(candidate, tanh), 3=o
// ---------------------------------------------------------------------------
__global__ __launch_bounds__(1024) void k_epilogue(
    const float* __restrict__ y, const float* __restrict__ qb,
    const unsigned* __restrict__ gmax, const float* __restrict__ c,
    float* __restrict__ out)
{
    __shared__ float sred[17];
    int tid = threadIdx.x;
    float v[4][4];

    // q1 = Q(x@W); yb = q1 + Q(b)
    #pragma unroll
    for (int g = 0; g < 4; ++g) {
        float s = qscale(__uint_as_float(gmax[g]));
        #pragma unroll
        for (int i = 0; i < 4; ++i) {
            int col = i * 1024 + tid;
            v[g][i] = quant1(y[g * 4096 + col], s) + qb[g * 4096 + col];
        }
    }

    // q2 = Q(yb); act = tanh/sigmoid(q2)
    for (int g = 0; g < 4; ++g) {
        float pm = 0.0f;
        #pragma unroll
        for (int i = 0; i < 4; ++i) pm = fmaxf(pm, fabsf(v[g][i]));
        float s = qscale(block_max_red(pm, sred));
        #pragma unroll
        for (int i = 0; i < 4; ++i) {
            float q = quant1(v[g][i], s);
            v[g][i] = (g == 2) ? tanhf(q) : (1.0f / (1.0f + expf(-q)));
        }
    }

    // q3 = Q(act)  -> v[0]=zf, v[1]=zi, v[2]=z, v[3]=zo
    for (int g = 0; g < 4; ++g) {
        float pm = 0.0f;
        #pragma unroll
        for (int i = 0; i < 4; ++i) pm = fmaxf(pm, fabsf(v[g][i]));
        float s = qscale(block_max_red(pm, sred));
        #pragma unroll
        for (int i = 0; i < 4; ++i) v[g][i] = quant1(v[g][i], s);
    }

    // memory = Q(z * zi)
    float mem[4];
    #pragma unroll
    for (int i = 0; i < 4; ++i) mem[i] = v[2][i] * v[1][i];
    quant_vec4(mem, sred);

    // cf = Q(c * zf)
    float cf[4];
    #pragma unroll
    for (int i = 0; i < 4; ++i) cf[i] = c[i * 1024 + tid] * v[0][i];
    quant_vec4(cf, sred);

    // c_new = Q(cf + memory)
    float cn[4];
    #pragma unroll
    for (int i = 0; i < 4; ++i) cn[i] = cf[i] + mem[i];
    quant_vec4(cn, sred);

    // t = Q(tanh(c_new))
    float tc[4];
    #pragma unroll
    for (int i = 0; i < 4; ++i) tc[i] = tanhf(cn[i]);
    quant_vec4(tc, sred);

    // h_new = Q(zo * t)
    float hn[4];
    #pragma unroll
    for (int i = 0; i < 4; ++i) hn[i] = v[3][i] * tc[i];
    quant_vec4(hn, sred);
    #pragma unroll
    for (int i = 0; i < 4; ++i) out[i * 1024 + tid] = hn[i];
}

// ---------------------------------------------------------------------------
extern "C" void kernel_launch(void* const* d_in, const int* in_sizes, int n_in,
                              void* d_out, int out_size, void* d_ws, size_t ws_size,
                              hipStream_t stream) {
    const float* x = (const float*)d_in[0];   // inputs [1,4096]
    const float* c = (const float*)d_in[1];   // c      [1,4096]
    const float* h = (const float*)d_in[2];   // h      [1,4096]
    Ptrs4 wts, bs;
    wts.p[0] = (const float*)d_in[3];  bs.p[0] = (const float*)d_in[4];   // Wf
    wts.p[1] = (const float*)d_in[5];  bs.p[1] = (const float*)d_in[6];   // Wi
    wts.p[2] = (const float*)d_in[7];  bs.p[2] = (const float*)d_in[8];   // Wc
    wts.p[3] = (const float*)d_in[9];  bs.p[3] = (const float*)d_in[10];  // Wo

    float* ws = (float*)d_ws;
    float* partials = ws;                           // 4*64*4096 = 1048576 floats (4 MiB)
    float* concat_q = ws + 1048576;                 // 8192 floats
    float* qb       = ws + 1048576 + 8192;          // 16384 floats
    float* yv       = ws + 1048576 + 8192 + 16384;  // 16384 floats
    unsigned* gmax  = (unsigned*)(ws + 1048576 + 8192 + 16384 + 16384);

    hipLaunchKernelGGL(k_prep,     dim3(5),           dim3(1024), 0, stream,
                       x, h, bs, concat_q, qb, gmax);
    hipLaunchKernelGGL(k_gemv,     dim3(KCHUNKS, 4),  dim3(256),  0, stream,
                       wts, concat_q, partials);
    hipLaunchKernelGGL(k_reduce,   dim3(64),          dim3(256),  0, stream,
                       partials, yv, gmax);
    hipLaunchKernelGGL(k_epilogue, dim3(1),           dim3(1024), 0, stream,
                       yv, qb, gmax, c, (float*)d_out);
}